// Round 14
// baseline (99.695 us; speedup 1.0000x reference)
//
#include <hip/hip_runtime.h>

static constexpr int N = 128;
static constexpr int F = 128;
static constexpr int H = 8;
static constexpr int NATTR = 3;
static constexpr int M = N * N;        // 16384
static constexpr int OUTW = 320;       // F + 8*16 + 8*8
static constexpr int MSL = 64;         // m-splits in edge attention
static constexpr int CH = M / MSL;     // 256
static constexpr float LOG2E = 1.4426950408889634f;

__device__ __forceinline__ float leaky(float x) { return fmaxf(x, 0.2f * x); }
__device__ __forceinline__ int swz(int m) { return m ^ ((m >> 3) & 7); }

// ---------------------------------------------------------------------------
// Edge-to-node attention: R7 skeleton + moments form + swizzled E tile.
// Block = (head-quad, n-tile 16, m-chunk 256), all 3 attrs x 4 heads.
// LDS: sV[4h][m] (edge logit, scaled), sEx[m][4] (E interleaved, swizzled).
// Inner loop: 8 ds_read_b128 per i-step (was 20, 8-way conflicted).
// part record = float4(mom0, mom1, mom2, sum) at [ms][a][n][h].
template <bool L1>
__global__ void __launch_bounds__(256)
k_ea(const float* __restrict__ E,      // [3][N][N]
     const float* __restrict__ xsrc,   // X (stride 0) | xh [3][N][128]
     int xStride,
     const float* __restrict__ Wn,     // [3][8][F][KW]
     const float* __restrict__ aes,    // [8][KW]
     const float* __restrict__ We0,    // [8][3][4]
     const float* __restrict__ aen,    // [8][KE]
     const float* __restrict__ We1,    // [8][32][2] (L1 only)
     const float* __restrict__ adj,    // [N][M]
     float* __restrict__ part) {       // [MSL][3][N][8][4]
    constexpr int KW = L1 ? 8 : 16;
    __shared__ __align__(16) float sV[4 * CH];    // 4 KB
    __shared__ __align__(16) float sEx[CH * 4];   // 4 KB (swizzled)
    __shared__ __align__(16) float sWv[12 * 128]; // 6 KB
    __shared__ float sVa[12];
    __shared__ float sWc[24];

    int b = blockIdx.x;
    int ms = b & (MSL - 1);
    int nt = (b >> 6) & 7;
    int h0 = (b >> 9) * 4;
    int tid = threadIdx.x;
    int r = tid >> 4, l = tid & 15;
    int n = nt * 16 + r;
    int m0 = ms * CH;

    // ---- stage wvec (for inline a_self): log2e * (Wn . aes) ----
    for (int idx = tid; idx < 12 * 128; idx += 256) {
        int c = idx >> 7, f = idx & 127;
        int a = c >> 2, h = h0 + (c & 3);
        const float* wp = Wn + ((size_t)(a * H + h) * F + f) * KW;
        const float* ap = aes + h * KW;
        float acc = 0.f;
#pragma unroll
        for (int k = 0; k < KW; ++k) acc += wp[k] * ap[k];
        sWv[idx] = acc * LOG2E;
    }
    if (L1) {
        if (tid < 24) {
            int hh = tid / 6, rem = tid % 6, at = rem >> 1, k2 = rem & 1;
            int h = h0 + hh;
            float acc = 0.f;
            for (int c = 0; c < 32; ++c)
                acc += We0[((c >> 2) * 3 + at) * 4 + (c & 3)] *
                       We1[(h * 32 + c) * 2 + k2];
            sWc[(hh * 3 + at) * 2 + k2] = acc;
        }
        __syncthreads();
    }
    // ---- sVa[hh][at] = log2e * (W . aen): edge-logit weights ----
    if (tid < 12) {
        int hh = tid >> 2 == 0 ? tid / 3 : tid / 3;  // hh = tid/3
        int at = tid % 3;
        hh = tid / 3;
        int h = h0 + hh;
        float acc = 0.f;
        if (!L1) {
#pragma unroll
            for (int k = 0; k < 4; ++k)
                acc += We0[(h * 3 + at) * 4 + k] * aen[h * 4 + k];
        } else {
#pragma unroll
            for (int k2 = 0; k2 < 2; ++k2)
                acc += sWc[(hh * 3 + at) * 2 + k2] * aen[h * 2 + k2];
        }
        sVa[hh * 3 + at] = acc * LOG2E;
    }
    __syncthreads();

    // ---- stage E tile (swizzled) + per-head edge logits sV ----
    for (int mm = tid; mm < CH; mm += 256) {
        int m = m0 + mm;
        float e0 = E[m], e1 = E[M + m], e2 = E[2 * M + m];
        int mw = swz(mm);
        sEx[mw * 4 + 0] = e0;
        sEx[mw * 4 + 1] = e1;
        sEx[mw * 4 + 2] = e2;
        sEx[mw * 4 + 3] = 0.f;
#pragma unroll
        for (int hh = 0; hh < 4; ++hh)
            sV[hh * CH + mm] = sVa[hh * 3 + 0] * e0 + sVa[hh * 3 + 1] * e1 +
                               sVa[hh * 3 + 2] * e2;
    }
    __syncthreads();

    // ---- a_self inline: lane-coop dot of x-row with sWv ----
    float u[NATTR][4];
#pragma unroll
    for (int a = 0; a < NATTR; ++a) {
        const float* xr = xsrc + (size_t)a * xStride + (size_t)n * F;
        float xv[8];
#pragma unroll
        for (int j = 0; j < 8; ++j) xv[j] = xr[l + 16 * j];
#pragma unroll
        for (int hh = 0; hh < 4; ++hh) {
            const float* wr = sWv + (a * 4 + hh) * 128;
            float d = 0.f;
#pragma unroll
            for (int j = 0; j < 8; ++j) d += xv[j] * wr[l + 16 * j];
#pragma unroll
            for (int off = 1; off < 16; off <<= 1) d += __shfl_xor(d, off);
            u[a][hh] = d;
        }
    }

    // ---- main loop over the 256-m chunk (8 b128 / i-step) ----
    float sm[4][NATTR], q0[4][NATTR], q1[4][NATTR], q2[4][NATTR];
#pragma unroll
    for (int hh = 0; hh < 4; ++hh)
#pragma unroll
        for (int a = 0; a < NATTR; ++a) {
            sm[hh][a] = 0.f;
            q0[hh][a] = 0.f; q1[hh][a] = 0.f; q2[hh][a] = 0.f;
        }

    const float* adjp = adj + (size_t)n * M + m0;
    for (int i = l * 4; i < CH; i += 64) {
        const float4 av = *(const float4*)(adjp + i);
        float4 ev[4];
#pragma unroll
        for (int hh = 0; hh < 4; ++hh)
            ev[hh] = *(const float4*)&sV[hh * CH + i];
#pragma unroll
        for (int j = 0; j < 4; ++j) {
            float adjv = (&av.x)[j] * LOG2E;
            const float4 ex = *(const float4*)&sEx[swz(i + j) * 4];
#pragma unroll
            for (int hh = 0; hh < 4; ++hh) {
                float vv = (&ev[hh].x)[j];
#pragma unroll
                for (int a = 0; a < NATTR; ++a) {
                    float t = u[a][hh] + vv;
                    float p = __builtin_amdgcn_exp2f(fmaxf(t, 0.2f * t) + adjv);
                    sm[hh][a] += p;
                    q0[hh][a] += p * ex.x;
                    q1[hh][a] += p * ex.y;
                    q2[hh][a] += p * ex.z;
                }
            }
        }
    }

    // ---- butterfly-reduce within each 16-lane row group ----
#pragma unroll
    for (int off = 1; off < 16; off <<= 1) {
#pragma unroll
        for (int hh = 0; hh < 4; ++hh)
#pragma unroll
            for (int a = 0; a < NATTR; ++a) {
                sm[hh][a] += __shfl_xor(sm[hh][a], off);
                q0[hh][a] += __shfl_xor(q0[hh][a], off);
                q1[hh][a] += __shfl_xor(q1[hh][a], off);
                q2[hh][a] += __shfl_xor(q2[hh][a], off);
            }
    }
    if (l == 0) {
#pragma unroll
        for (int hh = 0; hh < 4; ++hh)
#pragma unroll
            for (int a = 0; a < NATTR; ++a) {
                float* pp = part + (((size_t)ms * NATTR + a) * N + n) * 32 +
                            (h0 + hh) * 4;
                *(float4*)pp = make_float4(q0[hh][a], q1[hh][a], q2[hh][a],
                                           sm[hh][a]);
            }
    }
}

// ---------------------------------------------------------------------------
// Mid (R10-verified): block = (a, h, ntile of 32 rows) = 96 blocks. Reduces
// moments, W-fixup -> nf_e, inline feat, feat2, s2/n2.
template <int K, int KE, bool FIRST>
__global__ void __launch_bounds__(256)
k_mid(const float* __restrict__ xsrc,    // X (stride 0) | xh
      int xStride,
      const float* __restrict__ Wn,      // [3][8][F][K]
      const float* __restrict__ part,    // [MSL][3][N][8][4]
      const float* __restrict__ We0,     // [8][3][4]
      const float* __restrict__ We1,     // [8][32][2] (KE==2 only)
      const float* __restrict__ be,      // [8][KE]
      const float* __restrict__ Wct,     // [8][K+KE][K]
      const float* __restrict__ bct,     // [8][K]
      const float* __restrict__ ans,     // [3][8][K]
      const float* __restrict__ ann,     // [3][8][K]
      const float* __restrict__ X,       // FIRST copy src
      float* __restrict__ out,
      float* __restrict__ feat2,         // [3][8][N][16]
      float* __restrict__ s2,            // [3][8][N]
      float* __restrict__ n2) {          // [3][8][N]
    constexpr int CIN = K + KE;
    __shared__ __align__(16) float sWn[F * K];
    __shared__ __align__(16) float sW[CIN * K];
    __shared__ __align__(16) float sIn[32 * CIN];
    __shared__ __align__(16) float sF2[32 * K];

    int b = blockIdx.x;
    int nt = b & 3, h = (b >> 2) & 7, a = b >> 5;
    int n0 = nt * 32;
    int tid = threadIdx.x;

    for (int i = tid; i < F * K; i += 256)
        sWn[i] = Wn[(size_t)(a * H + h) * F * K + i];
    for (int i = tid; i < CIN * K; i += 256) sW[i] = Wct[h * CIN * K + i];

    // ---- moment reduce: 32 rows x 8 groups over MSL splits ----
    {
        int r = tid >> 3, g = tid & 7;
        int n = n0 + r;
        float m0 = 0.f, m1 = 0.f, m2 = 0.f, sv = 0.f;
        for (int ms = g; ms < MSL; ms += 8) {
            const float4 v = *(const float4*)(
                part + (((size_t)ms * NATTR + a) * N + n) * 32 + h * 4);
            m0 += v.x; m1 += v.y; m2 += v.z; sv += v.w;
        }
#pragma unroll
        for (int off = 1; off < 8; off <<= 1) {
            m0 += __shfl_xor(m0, off);
            m1 += __shfl_xor(m1, off);
            m2 += __shfl_xor(m2, off);
            sv += __shfl_xor(sv, off);
        }
        if (g == 0) {
            float inv = 1.f / sv;
            float mom[3] = {m0, m1, m2};
            if (KE == 4) {
#pragma unroll
                for (int k = 0; k < 4; ++k) {
                    float acc = 0.f;
#pragma unroll
                    for (int at = 0; at < 3; ++at)
                        acc += We0[(h * 3 + at) * 4 + k] * mom[at];
                    sIn[r * CIN + K + k] = acc * inv + be[h * 4 + k];
                }
            } else {
                float wc[3][2];
#pragma unroll
                for (int at = 0; at < 3; ++at) {
                    float w0 = 0.f, w1 = 0.f;
                    for (int c = 0; c < 32; ++c) {
                        float we0 = We0[((c >> 2) * 3 + at) * 4 + (c & 3)];
                        w0 += we0 * We1[(h * 32 + c) * 2 + 0];
                        w1 += we0 * We1[(h * 32 + c) * 2 + 1];
                    }
                    wc[at][0] = w0; wc[at][1] = w1;
                }
#pragma unroll
                for (int k = 0; k < 2; ++k) {
                    float acc = wc[0][k] * mom[0] + wc[1][k] * mom[1] +
                                wc[2][k] * mom[2];
                    sIn[r * CIN + K + k] = acc * inv + be[h * 2 + k];
                }
            }
        }
    }
    if (FIRST && h == 0) {
        for (int i = tid; i < 32 * F; i += 256) {
            int n = n0 + (i >> 7);
            int f = i & (F - 1);
            out[(n * NATTR + a) * OUTW + f] = X[n * F + f];
        }
    }
    __syncthreads();

    // ---- inline feat for the 32 rows ----
    for (int o = tid; o < 32 * K; o += 256) {
        int r = o / K, k = o % K;
        const float* xr = xsrc + (size_t)a * xStride + (size_t)(n0 + r) * F;
        float acc = 0.f;
        for (int f = 0; f < F; ++f) acc += xr[f] * sWn[f * K + k];
        sIn[r * CIN + k] = acc;
    }
    __syncthreads();

    // ---- feat2 + s2/n2 ----
    for (int o = tid; o < 32 * K; o += 256) {
        int r = o / K, k = o % K;
        float acc = bct[h * K + k];
        for (int c = 0; c < CIN; ++c) acc += sIn[r * CIN + c] * sW[c * K + k];
        sF2[o] = acc;
        feat2[((size_t)(a * H + h) * N + n0 + r) * 16 + k] = acc;
    }
    __syncthreads();
    if (tid < 32) {
        int r = tid;
        float ss = 0.f, nn = 0.f;
        for (int k = 0; k < K; ++k) {
            ss += sF2[r * K + k] * ans[(a * H + h) * K + k];
            nn += sF2[r * K + k] * ann[(a * H + h) * K + k];
        }
        s2[(a * H + h) * N + n0 + r] = ss;
        n2[(a * H + h) * N + n0 + r] = nn;
    }
}

// ---------------------------------------------------------------------------
// Node: block = (a, h, itile of 16 rows) = 192 blocks.
template <int K, bool FIRST>
__global__ void __launch_bounds__(256)
k_node(const float* __restrict__ feat2,   // [3][8][N][16]
       const float* __restrict__ s2,      // [3][8][N]
       const float* __restrict__ n2,      // [3][8][N]
       const float* __restrict__ Einfo,   // [3][N][N]
       const float* __restrict__ Amat,    // [3][N][N]
       const float* __restrict__ bn,      // [3][8][K]
       float* __restrict__ out, int outOff,
       float* __restrict__ xh_out,        // [3][N][128] or nullptr
       float* __restrict__ einfo_out) {   // [3][N][N] or nullptr
    __shared__ __align__(16) float sF2[N * K];
    __shared__ __align__(16) float sS2[N];
    __shared__ __align__(16) float sn2[N];
    __shared__ __align__(16) float sdE[N];
    __shared__ __align__(16) float scE[N];
    __shared__ __align__(16) float sAlpha[4 * N];
    __shared__ __align__(16) float sRed[256];

    int b = blockIdx.x;
    int itile = b & 7, h = (b >> 3) & 7, a = b >> 6;
    int tid = threadIdx.x;

    for (int i = tid; i < N * K; i += 256)
        sF2[i] = feat2[((size_t)(a * H + h) * N + i / K) * 16 + i % K];
    if (tid < N) {
        sS2[tid] = s2[(a * H + h) * N + tid];
        sn2[tid] = n2[(a * H + h) * N + tid];
    }
    __syncthreads();

    {
        int m = tid & 127, w = tid >> 7;
        const float* Ep = Einfo + (size_t)a * M;
        float dacc = 0.f, cacc = 0.f;
        for (int j = w * 64; j < w * 64 + 64; ++j) {
            float v = Ep[j * N + m];
            dacc += sn2[j] * v;
            cacc += v;
        }
        sRed[tid] = dacc;
        sAlpha[w * N + m] = cacc;
        __syncthreads();
        if (tid < N) {
            sdE[tid] = sRed[tid] + sRed[128 + tid];
            scE[tid] = sAlpha[tid] + sAlpha[N + tid];
        }
    }
    __syncthreads();

    for (int pass = 0; pass < 4; ++pass) {
        int r = tid >> 6;
        int lane = tid & 63;
        int i = itile * 16 + pass * 4 + r;
        float s = sS2[i];
        const float* Ap = Amat + ((size_t)a * N + i) * N;
        float v0 = leaky(s * scE[lane] + sdE[lane]) + Ap[lane];
        float v1 = leaky(s * scE[lane + 64] + sdE[lane + 64]) + Ap[lane + 64];
        float p0 = __expf(v0), p1 = __expf(v1);
        float ssum = p0 + p1;
#pragma unroll
        for (int off = 1; off < 64; off <<= 1) ssum += __shfl_xor(ssum, off);
        float inv = 1.f / ssum;
        float a0 = p0 * inv, a1 = p1 * inv;
        sAlpha[r * N + lane] = a0;
        sAlpha[r * N + lane + 64] = a1;
        if (FIRST && h == H - 1) {
            einfo_out[((size_t)a * N + i) * N + lane] = a0;
            einfo_out[((size_t)a * N + i) * N + lane + 64] = a1;
        }
        __syncthreads();
        {
            int rr = tid >> 6, g = (tid >> 4) & 3, k = tid & 15;
            float acc = 0.f;
            if (k < K) {
                for (int it = 0; it < 32; ++it) {
                    int mm = g + 4 * it;
                    acc += sAlpha[rr * N + mm] * sF2[mm * K + k];
                }
            }
            sRed[tid] = acc;
        }
        __syncthreads();
        {
            int rr = tid >> 6, k = tid & 63;
            if (k < K) {
                float tot = bn[(a * H + h) * K + k];
#pragma unroll
                for (int g = 0; g < 4; ++g) tot += sRed[rr * 64 + g * 16 + k];
                float e = tot > 0.f ? tot : __expf(tot) - 1.f;   // elu
                int i2 = itile * 16 + pass * 4 + rr;
                out[(i2 * NATTR + a) * OUTW + outOff + h * K + k] = e;
                if (FIRST)
                    xh_out[((size_t)a * N + i2) * F + h * K + k] = e;
            }
        }
        __syncthreads();
    }
}

// ---------------------------------------------------------------------------
extern "C" void kernel_launch(void* const* d_in, const int* in_sizes, int n_in,
                              void* d_out, int out_size, void* d_ws, size_t ws_size,
                              hipStream_t stream) {
    const float* X    = (const float*)d_in[0];
    const float* A    = (const float*)d_in[1];
    const float* E    = (const float*)d_in[2];
    const float* adj  = (const float*)d_in[3];
    const float* Wn0  = (const float*)d_in[4];
    const float* bn0  = (const float*)d_in[5];
    const float* an0s = (const float*)d_in[6];
    const float* an0n = (const float*)d_in[7];
    const float* Wn1  = (const float*)d_in[8];
    const float* bn1  = (const float*)d_in[9];
    const float* an1s = (const float*)d_in[10];
    const float* an1n = (const float*)d_in[11];
    const float* We0  = (const float*)d_in[12];
    const float* be0  = (const float*)d_in[13];
    const float* We1  = (const float*)d_in[14];
    const float* be1  = (const float*)d_in[15];
    const float* Wct0 = (const float*)d_in[16];
    const float* bct0 = (const float*)d_in[17];
    const float* Wct1 = (const float*)d_in[18];
    const float* bct1 = (const float*)d_in[19];
    const float* ae0s = (const float*)d_in[20];
    const float* ae0n = (const float*)d_in[21];
    const float* ae1s = (const float*)d_in[22];
    const float* ae1n = (const float*)d_in[23];
    float* out = (float*)d_out;

    float* p = (float*)d_ws;
    float* part  = p; p += (size_t)MSL * NATTR * N * 32;
    float* feat2 = p; p += NATTR * H * N * 16;
    float* s2b   = p; p += NATTR * H * N;
    float* n2b   = p; p += NATTR * H * N;
    float* einfo = p; p += NATTR * N * N;
    float* xh    = p; p += NATTR * N * F;

    // ---- layer 0 ----
    k_ea<false><<<dim3(2 * 8 * MSL), dim3(256), 0, stream>>>(
        E, X, 0, Wn0, ae0s, We0, ae0n, nullptr, adj, part);
    k_mid<16, 4, true><<<dim3(96), dim3(256), 0, stream>>>(
        X, 0, Wn0, part, We0, nullptr, be0, Wct0, bct0, an0s, an0n, X, out,
        feat2, s2b, n2b);
    k_node<16, true><<<dim3(192), dim3(256), 0, stream>>>(
        feat2, s2b, n2b, E, A, bn0, out, F, xh, einfo);

    // ---- layer 1 ----
    k_ea<true><<<dim3(2 * 8 * MSL), dim3(256), 0, stream>>>(
        E, xh, N * F, Wn1, ae1s, We0, ae1n, We1, adj, part);
    k_mid<8, 2, false><<<dim3(96), dim3(256), 0, stream>>>(
        xh, N * F, Wn1, part, We0, We1, be1, Wct1, bct1, an1s, an1n,
        nullptr, nullptr, feat2, s2b, n2b);
    k_node<8, false><<<dim3(192), dim3(256), 0, stream>>>(
        feat2, s2b, n2b, einfo, A, bn1, out, F + 128, nullptr, nullptr);
}

// Round 15
// 94.989 us; speedup vs baseline: 1.0495x; 1.0495x over previous
//
#include <hip/hip_runtime.h>

static constexpr int N = 128;
static constexpr int F = 128;
static constexpr int H = 8;
static constexpr int NATTR = 3;
static constexpr int M = N * N;        // 16384
static constexpr int OUTW = 320;       // F + 8*16 + 8*8
static constexpr int MSL = 64;         // m-splits in edge attention
static constexpr int CH = M / MSL;     // 256
static constexpr float LOG2E = 1.4426950408889634f;

__device__ __forceinline__ float leaky(float x) { return fmaxf(x, 0.2f * x); }
__device__ __forceinline__ int swz(int m) { return m ^ ((m >> 3) & 7); }

// ---------------------------------------------------------------------------
// Prep: aself[3][8][N] = LOG2E * ((xsrc @ Wn) · aes). 24 blocks x 128 thr.
template <int K>
__global__ void __launch_bounds__(128)
k_prep(const float* __restrict__ xsrc, int xStride,
       const float* __restrict__ Wn,   // [3][8][F][K]
       const float* __restrict__ aes,  // [8][K]
       float* __restrict__ aself) {    // [3][8][N]
    int a = blockIdx.x / H, h = blockIdx.x % H;
    __shared__ float wv[F];
    int tid = threadIdx.x;             // 128 = F = N
    {
        const float* wp = Wn + ((size_t)(a * H + h) * F + tid) * K;
        const float* ap = aes + h * K;
        float acc = 0.f;
#pragma unroll
        for (int k = 0; k < K; ++k) acc += wp[k] * ap[k];
        wv[tid] = acc;
    }
    __syncthreads();
    const float4* xr4 = (const float4*)(xsrc + (size_t)a * xStride + (size_t)tid * F);
    float acc = 0.f;
#pragma unroll 4
    for (int f = 0; f < F / 4; ++f) {
        float4 v = xr4[f];
        acc += v.x * wv[f * 4 + 0] + v.y * wv[f * 4 + 1] +
               v.z * wv[f * 4 + 2] + v.w * wv[f * 4 + 3];
    }
    aself[(a * H + h) * N + tid] = acc * LOG2E;
}

// ---------------------------------------------------------------------------
// Edge-to-node attention, moments form, I$-fit (no unroll of the i-loop).
// Block = (head-quad, n-tile 16, m-chunk 256), all 3 attrs x 4 heads.
// LDS: sV[4h][m] (edge logit, scaled), sEx[m][4] (E interleaved, swizzled).
// part record = float4(mom0, mom1, mom2, sum) at [a][n][h][ms].
template <bool L1>
__global__ void __launch_bounds__(256)
k_ea(const float* __restrict__ E,      // [3][N][N]
     const float* __restrict__ aself,  // [3][8][N] (log2e-scaled)
     const float* __restrict__ We0,    // [8][3][4]
     const float* __restrict__ aen,    // [8][KE]
     const float* __restrict__ We1,    // [8][32][2] (L1 only)
     const float* __restrict__ adj,    // [N][M]
     float* __restrict__ part) {       // [3][N][8][MSL][4]
    __shared__ __align__(16) float sV[4 * CH];    // 4 KB
    __shared__ __align__(16) float sEx[CH * 4];   // 4 KB (swizzled)
    __shared__ float sVa[12];
    __shared__ float sWc[24];

    int b = blockIdx.x;
    int ms = b & (MSL - 1);
    int nt = (b >> 6) & 7;
    int h0 = (b >> 9) * 4;
    int tid = threadIdx.x;
    int r = tid >> 4, l = tid & 15;
    int n = nt * 16 + r;
    int m0 = ms * CH;

    if (L1) {
        if (tid < 24) {
            int hh = tid / 6, rem = tid % 6, at = rem >> 1, k2 = rem & 1;
            int h = h0 + hh;
            float acc = 0.f;
            for (int c = 0; c < 32; ++c)
                acc += We0[((c >> 2) * 3 + at) * 4 + (c & 3)] *
                       We1[(h * 32 + c) * 2 + k2];
            sWc[(hh * 3 + at) * 2 + k2] = acc;
        }
        __syncthreads();
    }
    // ---- sVa[hh][at] = log2e * (W . aen): edge-logit weights ----
    if (tid < 12) {
        int hh = tid / 3, at = tid % 3;
        int h = h0 + hh;
        float acc = 0.f;
        if (!L1) {
#pragma unroll
            for (int k = 0; k < 4; ++k)
                acc += We0[(h * 3 + at) * 4 + k] * aen[h * 4 + k];
        } else {
#pragma unroll
            for (int k2 = 0; k2 < 2; ++k2)
                acc += sWc[(hh * 3 + at) * 2 + k2] * aen[h * 2 + k2];
        }
        sVa[hh * 3 + at] = acc * LOG2E;
    }
    __syncthreads();

    // ---- stage E tile (swizzled) + per-head edge logits sV ----
    for (int mm = tid; mm < CH; mm += 256) {
        int m = m0 + mm;
        float e0 = E[m], e1 = E[M + m], e2 = E[2 * M + m];
        int mw = swz(mm);
        sEx[mw * 4 + 0] = e0;
        sEx[mw * 4 + 1] = e1;
        sEx[mw * 4 + 2] = e2;
        sEx[mw * 4 + 3] = 0.f;
#pragma unroll
        for (int hh = 0; hh < 4; ++hh)
            sV[hh * CH + mm] = sVa[hh * 3 + 0] * e0 + sVa[hh * 3 + 1] * e1 +
                               sVa[hh * 3 + 2] * e2;
    }

    // ---- a_self (precomputed, L2-hot) ----
    float u[NATTR][4];
#pragma unroll
    for (int a = 0; a < NATTR; ++a)
#pragma unroll
        for (int hh = 0; hh < 4; ++hh)
            u[a][hh] = aself[(a * H + h0 + hh) * N + n];
    __syncthreads();

    // ---- main loop over the 256-m chunk; NOT unrolled (I$ fit) ----
    float sm[4][NATTR], q0[4][NATTR], q1[4][NATTR], q2[4][NATTR];
#pragma unroll
    for (int hh = 0; hh < 4; ++hh)
#pragma unroll
        for (int a = 0; a < NATTR; ++a) {
            sm[hh][a] = 0.f;
            q0[hh][a] = 0.f; q1[hh][a] = 0.f; q2[hh][a] = 0.f;
        }

    const float* adjp = adj + (size_t)n * M + m0;
#pragma unroll 1
    for (int i = l * 4; i < CH; i += 64) {
        const float4 av = *(const float4*)(adjp + i);
        float4 ev[4];
#pragma unroll
        for (int hh = 0; hh < 4; ++hh)
            ev[hh] = *(const float4*)&sV[hh * CH + i];
#pragma unroll
        for (int j = 0; j < 4; ++j) {
            float adjv = (&av.x)[j] * LOG2E;
            const float4 ex = *(const float4*)&sEx[swz(i + j) * 4];
#pragma unroll
            for (int hh = 0; hh < 4; ++hh) {
                float vv = (&ev[hh].x)[j];
#pragma unroll
                for (int a = 0; a < NATTR; ++a) {
                    float t = u[a][hh] + vv;
                    float p = __builtin_amdgcn_exp2f(fmaxf(t, 0.2f * t) + adjv);
                    sm[hh][a] += p;
                    q0[hh][a] += p * ex.x;
                    q1[hh][a] += p * ex.y;
                    q2[hh][a] += p * ex.z;
                }
            }
        }
    }

    // ---- butterfly-reduce within each 16-lane row group ----
#pragma unroll
    for (int off = 1; off < 16; off <<= 1) {
#pragma unroll
        for (int hh = 0; hh < 4; ++hh)
#pragma unroll
            for (int a = 0; a < NATTR; ++a) {
                sm[hh][a] += __shfl_xor(sm[hh][a], off);
                q0[hh][a] += __shfl_xor(q0[hh][a], off);
                q1[hh][a] += __shfl_xor(q1[hh][a], off);
                q2[hh][a] += __shfl_xor(q2[hh][a], off);
            }
    }
    if (l == 0) {
#pragma unroll
        for (int hh = 0; hh < 4; ++hh)
#pragma unroll
            for (int a = 0; a < NATTR; ++a) {
                float* pp = part + ((((size_t)a * N + n) * H + h0 + hh) * MSL + ms) * 4;
                *(float4*)pp = make_float4(q0[hh][a], q1[hh][a], q2[hh][a],
                                           sm[hh][a]);
            }
    }
}

// ---------------------------------------------------------------------------
// Mid: block = (a, h, ntile of 32 rows) = 96 blocks. Reduces moments
// (contiguous [ms] runs), W-fixup -> nf_e, inline feat, feat2, s2/n2.
template <int K, int KE, bool FIRST>
__global__ void __launch_bounds__(256)
k_mid(const float* __restrict__ xsrc,    // X (stride 0) | xh
      int xStride,
      const float* __restrict__ Wn,      // [3][8][F][K]
      const float* __restrict__ part,    // [3][N][8][MSL][4]
      const float* __restrict__ We0,     // [8][3][4]
      const float* __restrict__ We1,     // [8][32][2] (KE==2 only)
      const float* __restrict__ be,      // [8][KE]
      const float* __restrict__ Wct,     // [8][K+KE][K]
      const float* __restrict__ bct,     // [8][K]
      const float* __restrict__ ans,     // [3][8][K]
      const float* __restrict__ ann,     // [3][8][K]
      const float* __restrict__ X,       // FIRST copy src
      float* __restrict__ out,
      float* __restrict__ feat2,         // [3][8][N][16]
      float* __restrict__ s2,            // [3][8][N]
      float* __restrict__ n2) {          // [3][8][N]
    constexpr int CIN = K + KE;
    __shared__ __align__(16) float sWn[F * K];
    __shared__ __align__(16) float sW[CIN * K];
    __shared__ __align__(16) float sIn[32 * CIN];
    __shared__ __align__(16) float sF2[32 * K];

    int b = blockIdx.x;
    int nt = b & 3, h = (b >> 2) & 7, a = b >> 5;
    int n0 = nt * 32;
    int tid = threadIdx.x;

    for (int i = tid; i < F * K; i += 256)
        sWn[i] = Wn[(size_t)(a * H + h) * F * K + i];
    for (int i = tid; i < CIN * K; i += 256) sW[i] = Wct[h * CIN * K + i];

    // ---- moment reduce: 32 rows x 8 groups over MSL splits (coalesced) ----
    {
        int r = tid >> 3, g = tid & 7;
        int n = n0 + r;
        const float* pp = part + (((size_t)a * N + n) * H + h) * MSL * 4;
        float m0 = 0.f, m1 = 0.f, m2 = 0.f, sv = 0.f;
        for (int ms = g; ms < MSL; ms += 8) {
            const float4 v = *(const float4*)(pp + ms * 4);
            m0 += v.x; m1 += v.y; m2 += v.z; sv += v.w;
        }
#pragma unroll
        for (int off = 1; off < 8; off <<= 1) {
            m0 += __shfl_xor(m0, off);
            m1 += __shfl_xor(m1, off);
            m2 += __shfl_xor(m2, off);
            sv += __shfl_xor(sv, off);
        }
        if (g == 0) {
            float inv = 1.f / sv;
            float mom[3] = {m0, m1, m2};
            if (KE == 4) {
#pragma unroll
                for (int k = 0; k < 4; ++k) {
                    float acc = 0.f;
#pragma unroll
                    for (int at = 0; at < 3; ++at)
                        acc += We0[(h * 3 + at) * 4 + k] * mom[at];
                    sIn[r * CIN + K + k] = acc * inv + be[h * 4 + k];
                }
            } else {
                float wc[3][2];
#pragma unroll
                for (int at = 0; at < 3; ++at) {
                    float w0 = 0.f, w1 = 0.f;
                    for (int c = 0; c < 32; ++c) {
                        float we0 = We0[((c >> 2) * 3 + at) * 4 + (c & 3)];
                        w0 += we0 * We1[(h * 32 + c) * 2 + 0];
                        w1 += we0 * We1[(h * 32 + c) * 2 + 1];
                    }
                    wc[at][0] = w0; wc[at][1] = w1;
                }
#pragma unroll
                for (int k = 0; k < 2; ++k) {
                    float acc = wc[0][k] * mom[0] + wc[1][k] * mom[1] +
                                wc[2][k] * mom[2];
                    sIn[r * CIN + K + k] = acc * inv + be[h * 2 + k];
                }
            }
        }
    }
    if (FIRST && h == 0) {
        for (int i = tid; i < 32 * F; i += 256) {
            int n = n0 + (i >> 7);
            int f = i & (F - 1);
            out[(n * NATTR + a) * OUTW + f] = X[n * F + f];
        }
    }
    __syncthreads();

    // ---- inline feat for the 32 rows ----
    for (int o = tid; o < 32 * K; o += 256) {
        int r = o / K, k = o % K;
        const float* xr = xsrc + (size_t)a * xStride + (size_t)(n0 + r) * F;
        float acc = 0.f;
        for (int f = 0; f < F; ++f) acc += xr[f] * sWn[f * K + k];
        sIn[r * CIN + k] = acc;
    }
    __syncthreads();

    // ---- feat2 + s2/n2 ----
    for (int o = tid; o < 32 * K; o += 256) {
        int r = o / K, k = o % K;
        float acc = bct[h * K + k];
        for (int c = 0; c < CIN; ++c) acc += sIn[r * CIN + c] * sW[c * K + k];
        sF2[o] = acc;
        feat2[((size_t)(a * H + h) * N + n0 + r) * 16 + k] = acc;
    }
    __syncthreads();
    if (tid < 32) {
        int r = tid;
        float ss = 0.f, nn = 0.f;
        for (int k = 0; k < K; ++k) {
            ss += sF2[r * K + k] * ans[(a * H + h) * K + k];
            nn += sF2[r * K + k] * ann[(a * H + h) * K + k];
        }
        s2[(a * H + h) * N + n0 + r] = ss;
        n2[(a * H + h) * N + n0 + r] = nn;
    }
}

// ---------------------------------------------------------------------------
// Node: block = (a, h, itile of 16 rows) = 192 blocks.
template <int K, bool FIRST>
__global__ void __launch_bounds__(256)
k_node(const float* __restrict__ feat2,   // [3][8][N][16]
       const float* __restrict__ s2,      // [3][8][N]
       const float* __restrict__ n2,      // [3][8][N]
       const float* __restrict__ Einfo,   // [3][N][N]
       const float* __restrict__ Amat,    // [3][N][N]
       const float* __restrict__ bn,      // [3][8][K]
       float* __restrict__ out, int outOff,
       float* __restrict__ xh_out,        // [3][N][128] or nullptr
       float* __restrict__ einfo_out) {   // [3][N][N] or nullptr
    __shared__ __align__(16) float sF2[N * K];
    __shared__ __align__(16) float sS2[N];
    __shared__ __align__(16) float sn2[N];
    __shared__ __align__(16) float sdE[N];
    __shared__ __align__(16) float scE[N];
    __shared__ __align__(16) float sAlpha[4 * N];
    __shared__ __align__(16) float sRed[256];

    int b = blockIdx.x;
    int itile = b & 7, h = (b >> 3) & 7, a = b >> 6;
    int tid = threadIdx.x;

    for (int i = tid; i < N * K; i += 256)
        sF2[i] = feat2[((size_t)(a * H + h) * N + i / K) * 16 + i % K];
    if (tid < N) {
        sS2[tid] = s2[(a * H + h) * N + tid];
        sn2[tid] = n2[(a * H + h) * N + tid];
    }
    __syncthreads();

    {
        int m = tid & 127, w = tid >> 7;
        const float* Ep = Einfo + (size_t)a * M;
        float dacc = 0.f, cacc = 0.f;
        for (int j = w * 64; j < w * 64 + 64; ++j) {
            float v = Ep[j * N + m];
            dacc += sn2[j] * v;
            cacc += v;
        }
        sRed[tid] = dacc;
        sAlpha[w * N + m] = cacc;
        __syncthreads();
        if (tid < N) {
            sdE[tid] = sRed[tid] + sRed[128 + tid];
            scE[tid] = sAlpha[tid] + sAlpha[N + tid];
        }
    }
    __syncthreads();

    for (int pass = 0; pass < 4; ++pass) {
        int r = tid >> 6;
        int lane = tid & 63;
        int i = itile * 16 + pass * 4 + r;
        float s = sS2[i];
        const float* Ap = Amat + ((size_t)a * N + i) * N;
        float v0 = leaky(s * scE[lane] + sdE[lane]) + Ap[lane];
        float v1 = leaky(s * scE[lane + 64] + sdE[lane + 64]) + Ap[lane + 64];
        float p0 = __expf(v0), p1 = __expf(v1);
        float ssum = p0 + p1;
#pragma unroll
        for (int off = 1; off < 64; off <<= 1) ssum += __shfl_xor(ssum, off);
        float inv = 1.f / ssum;
        float a0 = p0 * inv, a1 = p1 * inv;
        sAlpha[r * N + lane] = a0;
        sAlpha[r * N + lane + 64] = a1;
        if (FIRST && h == H - 1) {
            einfo_out[((size_t)a * N + i) * N + lane] = a0;
            einfo_out[((size_t)a * N + i) * N + lane + 64] = a1;
        }
        __syncthreads();
        {
            int rr = tid >> 6, g = (tid >> 4) & 3, k = tid & 15;
            float acc = 0.f;
            if (k < K) {
                for (int it = 0; it < 32; ++it) {
                    int mm = g + 4 * it;
                    acc += sAlpha[rr * N + mm] * sF2[mm * K + k];
                }
            }
            sRed[tid] = acc;
        }
        __syncthreads();
        {
            int rr = tid >> 6, k = tid & 63;
            if (k < K) {
                float tot = bn[(a * H + h) * K + k];
#pragma unroll
                for (int g = 0; g < 4; ++g) tot += sRed[rr * 64 + g * 16 + k];
                float e = tot > 0.f ? tot : __expf(tot) - 1.f;   // elu
                int i2 = itile * 16 + pass * 4 + rr;
                out[(i2 * NATTR + a) * OUTW + outOff + h * K + k] = e;
                if (FIRST)
                    xh_out[((size_t)a * N + i2) * F + h * K + k] = e;
            }
        }
        __syncthreads();
    }
}

// ---------------------------------------------------------------------------
extern "C" void kernel_launch(void* const* d_in, const int* in_sizes, int n_in,
                              void* d_out, int out_size, void* d_ws, size_t ws_size,
                              hipStream_t stream) {
    const float* X    = (const float*)d_in[0];
    const float* A    = (const float*)d_in[1];
    const float* E    = (const float*)d_in[2];
    const float* adj  = (const float*)d_in[3];
    const float* Wn0  = (const float*)d_in[4];
    const float* bn0  = (const float*)d_in[5];
    const float* an0s = (const float*)d_in[6];
    const float* an0n = (const float*)d_in[7];
    const float* Wn1  = (const float*)d_in[8];
    const float* bn1  = (const float*)d_in[9];
    const float* an1s = (const float*)d_in[10];
    const float* an1n = (const float*)d_in[11];
    const float* We0  = (const float*)d_in[12];
    const float* be0  = (const float*)d_in[13];
    const float* We1  = (const float*)d_in[14];
    const float* be1  = (const float*)d_in[15];
    const float* Wct0 = (const float*)d_in[16];
    const float* bct0 = (const float*)d_in[17];
    const float* Wct1 = (const float*)d_in[18];
    const float* bct1 = (const float*)d_in[19];
    const float* ae0s = (const float*)d_in[20];
    const float* ae0n = (const float*)d_in[21];
    const float* ae1s = (const float*)d_in[22];
    const float* ae1n = (const float*)d_in[23];
    float* out = (float*)d_out;

    float* p = (float*)d_ws;
    float* part  = p; p += (size_t)NATTR * N * H * MSL * 4;
    float* aself = p; p += NATTR * H * N;
    float* feat2 = p; p += NATTR * H * N * 16;
    float* s2b   = p; p += NATTR * H * N;
    float* n2b   = p; p += NATTR * H * N;
    float* einfo = p; p += NATTR * N * N;
    float* xh    = p; p += NATTR * N * F;

    // ---- layer 0 ----
    k_prep<16><<<dim3(24), dim3(128), 0, stream>>>(X, 0, Wn0, ae0s, aself);
    k_ea<false><<<dim3(2 * 8 * MSL), dim3(256), 0, stream>>>(
        E, aself, We0, ae0n, nullptr, adj, part);
    k_mid<16, 4, true><<<dim3(96), dim3(256), 0, stream>>>(
        X, 0, Wn0, part, We0, nullptr, be0, Wct0, bct0, an0s, an0n, X, out,
        feat2, s2b, n2b);
    k_node<16, true><<<dim3(192), dim3(256), 0, stream>>>(
        feat2, s2b, n2b, E, A, bn0, out, F, xh, einfo);

    // ---- layer 1 ----
    k_prep<8><<<dim3(24), dim3(128), 0, stream>>>(xh, N * F, Wn1, ae1s, aself);
    k_ea<true><<<dim3(2 * 8 * MSL), dim3(256), 0, stream>>>(
        E, aself, We0, ae1n, We1, adj, part);
    k_mid<8, 2, false><<<dim3(96), dim3(256), 0, stream>>>(
        xh, N * F, Wn1, part, We0, We1, be1, Wct1, bct1, an1s, an1n,
        nullptr, nullptr, feat2, s2b, n2b);
    k_node<8, false><<<dim3(192), dim3(256), 0, stream>>>(
        feat2, s2b, n2b, einfo, A, bn1, out, F + 128, nullptr, nullptr);
}